// Round 7
// baseline (384.078 us; speedup 1.0000x reference)
//
#include <hip/hip_runtime.h>

#define B_   2
#define T_   2048
#define C_   768
#define H_   12
#define HD_  64
#define M_   (B_ * T_)    // 4096 rows
#define N3_  (3 * C_)     // 2304
#define KB_  (C_ * 2)     // 1536 bytes per row (bf16)

typedef __bf16 bf16_t;
typedef bf16_t bf16x8 __attribute__((ext_vector_type(8)));
typedef float  floatx4 __attribute__((ext_vector_type(4)));

__device__ inline floatx4 mfma_bf16(bf16x8 a, bf16x8 b, floatx4 c) {
    return __builtin_amdgcn_mfma_f32_16x16x32_bf16(a, b, c, 0, 0, 0);
}

__device__ __forceinline__ void async_copy16(const void* g, void* l) {
    __builtin_amdgcn_global_load_lds(
        (const __attribute__((address_space(1))) void*)g,
        (__attribute__((address_space(3))) void*)l, 16, 0, 0);
}

// ---------------------------------------------------------------------------
// Shared 128x128-tile GEMM mainloop.
// ---------------------------------------------------------------------------
__device__ __forceinline__ void stage8k(const char* tile, char* ldsbase,
                                        int k0b, int wave, int lane) {
#pragma unroll
    for (int i = 0; i < 2; ++i) {
        int p = (wave * 2 + i) * 64 + lane;     // 16B slot index 0..511
        int r = p >> 2, slot = p & 3;
        int g = slot ^ ((r >> 1) & 3);
        async_copy16(tile + (size_t)r * KB_ + k0b + g * 16, ldsbase + p * 16);
    }
}

__device__ __forceinline__ bf16x8 frag_read(const char* ldsbase, int row, int quad) {
    int slot = quad ^ ((row >> 1) & 3);
    return *(const bf16x8*)(ldsbase + row * 64 + slot * 16);
}

template<bool TRIPLE>
__device__ __forceinline__ void gemm_loop(
    const char* Ah, const char* Al, const char* Bh, const char* Bl,
    char* lds, floatx4 (&acc)[4][4])
{
    int tid = threadIdx.x, lane = tid & 63, wave = tid >> 6;
    int l15 = lane & 15, quad = lane >> 4;
    int wr = wave >> 1, wc = wave & 1;
    char* LAh = lds;
    char* LAl = lds + 8192;
    char* LBh = lds + (TRIPLE ? 16384 : 8192);
    char* LBl = lds + 24576;
#pragma unroll 1
    for (int k0 = 0; k0 < KB_; k0 += 64) {       // 32 bf16 per chunk
        __syncthreads();
        stage8k(Ah, LAh, k0, wave, lane);
        if (TRIPLE) stage8k(Al, LAl, k0, wave, lane);
        stage8k(Bh, LBh, k0, wave, lane);
        if (TRIPLE) stage8k(Bl, LBl, k0, wave, lane);
        __syncthreads();
        bf16x8 ah[4], al[4], bh[4], bl[4];
#pragma unroll
        for (int t = 0; t < 4; ++t) {
            ah[t] = frag_read(LAh, wr * 64 + t * 16 + l15, quad);
            bh[t] = frag_read(LBh, wc * 64 + t * 16 + l15, quad);
            if (TRIPLE) {
                al[t] = frag_read(LAl, wr * 64 + t * 16 + l15, quad);
                bl[t] = frag_read(LBl, wc * 64 + t * 16 + l15, quad);
            }
        }
#pragma unroll
        for (int mi = 0; mi < 4; ++mi)
#pragma unroll
            for (int ni = 0; ni < 4; ++ni) {
                acc[mi][ni] = mfma_bf16(ah[mi], bh[ni], acc[mi][ni]);
                if (TRIPLE) {
                    acc[mi][ni] = mfma_bf16(ah[mi], bl[ni], acc[mi][ni]);
                    acc[mi][ni] = mfma_bf16(al[mi], bh[ni], acc[mi][ni]);
                }
            }
    }
}

// ---------------------------------------------------------------------------
// K0: fp32 -> bf16 hi/lo split (and plain convert)
// ---------------------------------------------------------------------------
__global__ __launch_bounds__(256) void split_f32(
    const float* __restrict__ src, bf16_t* __restrict__ hi,
    bf16_t* __restrict__ lo, int n)
{
    int i = blockIdx.x * 256 + threadIdx.x;
    if (i < n) {
        float f = src[i];
        bf16_t h = (bf16_t)f;
        hi[i] = h;
        lo[i] = (bf16_t)(f - (float)h);
    }
}

__global__ __launch_bounds__(256) void conv_f32(
    const float* __restrict__ src, bf16_t* __restrict__ dst, int n)
{
    int i = blockIdx.x * 256 + threadIdx.x;
    if (i < n) dst[i] = (bf16_t)src[i];
}

// ---------------------------------------------------------------------------
// K1: qkv = x @ w_attn^T + b_attn.  q/k sections bf16x3; v section bf16.
// q stored PRE-SCALED by 0.125.
// ---------------------------------------------------------------------------
__global__ __launch_bounds__(256) void qkv_gemm(
    const bf16_t* __restrict__ x_hi, const bf16_t* __restrict__ x_lo,
    const bf16_t* __restrict__ w_hi, const bf16_t* __restrict__ w_lo,
    const float* __restrict__ bias, const float* __restrict__ selw,
    bf16_t* __restrict__ q_hi, bf16_t* __restrict__ q_lo,
    bf16_t* __restrict__ kw_hi, bf16_t* __restrict__ kw_lo,
    bf16_t* __restrict__ k_b, bf16_t* __restrict__ v_b)
{
    extern __shared__ char lds[];
    int m0 = blockIdx.x * 128, n0 = blockIdx.y * 128;
    floatx4 acc[4][4];
#pragma unroll
    for (int i = 0; i < 4; ++i)
#pragma unroll
        for (int j = 0; j < 4; ++j) acc[i][j] = (floatx4){0.f, 0.f, 0.f, 0.f};
    if (n0 >= 2 * C_) {   // v section: single-precision bf16 path
        gemm_loop<false>((const char*)(x_hi + (size_t)m0 * C_), nullptr,
                         (const char*)(w_hi + (size_t)n0 * C_), nullptr, lds, acc);
    } else {
        gemm_loop<true>((const char*)(x_hi + (size_t)m0 * C_),
                        (const char*)(x_lo + (size_t)m0 * C_),
                        (const char*)(w_hi + (size_t)n0 * C_),
                        (const char*)(w_lo + (size_t)n0 * C_), lds, acc);
    }

    int tid = threadIdx.x, lane = tid & 63, wave = tid >> 6;
    int l15 = lane & 15, quad = lane >> 4;
    int wr = wave >> 1, wc = wave & 1;
    int cb = n0 + wc * 64;   // wave-uniform: section (q/k/v) is uniform
#pragma unroll
    for (int ni = 0; ni < 4; ++ni) {
        int col = cb + ni * 16 + l15;
        float bb = bias[col];
#pragma unroll
        for (int mi = 0; mi < 4; ++mi)
#pragma unroll
            for (int r = 0; r < 4; ++r) {
                int row = m0 + wr * 64 + mi * 16 + quad * 4 + r;
                float v = acc[mi][ni][r] + bb;
                if (cb < C_) {
                    float vs = v * 0.125f;           // fold softmax scale
                    bf16_t h = (bf16_t)vs;
                    q_hi[(size_t)row * C_ + col] = h;
                    q_lo[(size_t)row * C_ + col] = (bf16_t)(vs - (float)h);
                } else if (cb < 2 * C_) {
                    int c2 = col - C_;
                    k_b[(size_t)row * C_ + c2] = (bf16_t)v;
                    float kw = v * selw[c2 >> 6];
                    bf16_t h = (bf16_t)kw;
                    kw_hi[(size_t)row * C_ + c2] = h;
                    kw_lo[(size_t)row * C_ + c2] = (bf16_t)(kw - (float)h);
                } else {
                    v_b[(size_t)row * C_ + (col - 2 * C_)] = (bf16_t)v;
                }
            }
    }
}

// ---------------------------------------------------------------------------
// K2: S[b,i,j] = (1<=j<i) ? relu(q_i . kw_j) : 0   (bf16x3; 0.125 pre-folded)
// ---------------------------------------------------------------------------
__global__ __launch_bounds__(256) void s_gemm(
    const bf16_t* __restrict__ q_hi, const bf16_t* __restrict__ q_lo,
    const bf16_t* __restrict__ kw_hi, const bf16_t* __restrict__ kw_lo,
    float* __restrict__ SF)
{
    extern __shared__ char lds[];
    int i0 = blockIdx.x * 128, j0 = blockIdx.y * 128, b = blockIdx.z;
    float* out = SF + (size_t)b * T_ * T_;
    int tid = threadIdx.x;
    if (j0 > i0) {   // fully-masked tile: zero-fill (scan needs init'd buffer)
        float4 z = {0.f, 0.f, 0.f, 0.f};
        float* p = out + (size_t)(i0 + (tid >> 1)) * T_ + j0 + (tid & 1) * 64;
#pragma unroll
        for (int c = 0; c < 16; ++c) ((float4*)p)[c] = z;
        return;
    }
    floatx4 acc[4][4];
#pragma unroll
    for (int i = 0; i < 4; ++i)
#pragma unroll
        for (int j = 0; j < 4; ++j) acc[i][j] = (floatx4){0.f, 0.f, 0.f, 0.f};
    size_t arow = ((size_t)b * T_ + i0) * C_;
    size_t brow = ((size_t)b * T_ + j0) * C_;
    gemm_loop<true>((const char*)(q_hi + arow), (const char*)(q_lo + arow),
                    (const char*)(kw_hi + brow), (const char*)(kw_lo + brow),
                    lds, acc);

    int lane = tid & 63, wave = tid >> 6;
    int l15 = lane & 15, quad = lane >> 4;
    int wr = wave >> 1, wc = wave & 1;
#pragma unroll
    for (int ni = 0; ni < 4; ++ni) {
        int j = j0 + wc * 64 + ni * 16 + l15;
#pragma unroll
        for (int mi = 0; mi < 4; ++mi)
#pragma unroll
            for (int r = 0; r < 4; ++r) {
                int i = i0 + wr * 64 + mi * 16 + quad * 4 + r;
                float s = acc[mi][ni][r];
                s = (j >= 1 && j < i) ? fmaxf(s, 0.f) : 0.f;
                out[(size_t)i * T_ + j] = s;
            }
    }
}

// ---------------------------------------------------------------------------
// K3-K5: per-column exclusive prefix sum over rows (FF_shifted), 3-phase.
// ---------------------------------------------------------------------------
#define SEG_    16
#define SEGLEN_ (T_ / SEG_)  // 128

__global__ __launch_bounds__(256) void scan_seg_sum(
    const float* __restrict__ SF, float* __restrict__ segsum)
{
    int gid  = blockIdx.x * 256 + threadIdx.x;
    int j    = gid & (T_ - 1);
    int rest = gid >> 11;
    int seg  = rest & (SEG_ - 1);
    int b    = rest >> 4;
    const float* col = SF + (size_t)b * T_ * T_ + (size_t)(seg * SEGLEN_) * T_ + j;
    float s = 0.f;
#pragma unroll 8
    for (int i = 0; i < SEGLEN_; ++i) s += col[(size_t)i * T_];
    segsum[((size_t)b * SEG_ + seg) * T_ + j] = s;
}

__global__ __launch_bounds__(256) void scan_seg_excl(float* __restrict__ segsum)
{
    int gid = blockIdx.x * 256 + threadIdx.x;
    int j = gid & (T_ - 1);
    int b = gid >> 11;
    float run = 0.f;
#pragma unroll
    for (int s = 0; s < SEG_; ++s) {
        size_t idx = ((size_t)b * SEG_ + s) * T_ + j;
        float v = segsum[idx];
        segsum[idx] = run;
        run += v;
    }
}

__global__ __launch_bounds__(256) void scan_apply(
    float* __restrict__ SF, const float* __restrict__ segsum)
{
    int gid  = blockIdx.x * 256 + threadIdx.x;
    int j    = gid & (T_ - 1);
    int rest = gid >> 11;
    int seg  = rest & (SEG_ - 1);
    int b    = rest >> 4;
    float run = segsum[((size_t)b * SEG_ + seg) * T_ + j];
    float* col = SF + (size_t)b * T_ * T_ + (size_t)(seg * SEGLEN_) * T_ + j;
#pragma unroll 4
    for (int i = 0; i < SEGLEN_; ++i) {
        float s = col[(size_t)i * T_];
        col[(size_t)i * T_] = run;   // exclusive: FF_shifted[i,j]
        run += s;
    }
}

// ---------------------------------------------------------------------------
// K5b: V -> V^T  (per (b,h): [T][64] -> [64][T]).
// ---------------------------------------------------------------------------
__global__ __launch_bounds__(256) void vt_kernel(
    const bf16_t* __restrict__ v_b, bf16_t* __restrict__ vt)
{
    __shared__ bf16_t tile[64][72];
    int t0 = blockIdx.x * 64, h = blockIdx.y, b = blockIdx.z;
    int tid = threadIdx.x;
    int r = tid >> 2, sl = tid & 3;           // r: 0..63, sl: 0..3 (16 elems each)
    const bf16_t* src = v_b + ((size_t)(b * T_ + t0 + r)) * C_ + h * HD_ + sl * 16;
    *(int4*)&tile[r][sl * 16]     = *(const int4*)src;
    *(int4*)&tile[r][sl * 16 + 8] = *(const int4*)(src + 8);
    __syncthreads();
    int hd = tid >> 2, q = tid & 3;
#pragma unroll
    for (int half = 0; half < 2; ++half) {
        int c0 = (q * 2 + half) * 8;
        union { int4 i4; bf16_t e[8]; } u;
#pragma unroll
        for (int kk = 0; kk < 8; ++kk) u.e[kk] = tile[c0 + kk][hd];
        *(int4*)(vt + ((size_t)(b * H_ + h) * HD_ + hd) * T_ + t0 + c0) = u.i4;
    }
}

// ---------------------------------------------------------------------------
// K6 (v5): v4 structure + ALL loads (K, V^T, FF) issued at iteration TOP.
// v4's asm waitcnt carries a full memory clobber, so loads placed after it
// could not be hoisted -> 3 serialized global-latency exposures per iter.
// With all loads issued before the first MFMA, vmcnt's in-order FIFO lets
// the compiler wait only for K before QK while V/FF stay in flight through
// the LDS roundtrip + softmax.  __launch_bounds__(256,4) pins VGPR<=128 so
// 4 waves/SIMD stay resident.
// ---------------------------------------------------------------------------
__global__ __launch_bounds__(256, 4) void attn_kernel(
    const bf16_t* __restrict__ q_b, const bf16_t* __restrict__ k_b,
    const bf16_t* __restrict__ vt_g, const float* __restrict__ FF,
    bf16_t* __restrict__ y_b)
{
    __shared__ __align__(16) float LS[4][16][68];   // qk roundtrip; reused as Om
    __shared__ float Ml[4][16][2];

    int tid = threadIdx.x, lane = tid & 63, wave = tid >> 6;
    int l15 = lane & 15, quad = lane >> 4;
    int h = blockIdx.y, b = blockIdx.z;
    int itile = (int)gridDim.x - 1 - (int)blockIdx.x;   // heavy-first
    int i0 = itile * 16, imax = i0 + 15;
    const floatx4 fzero = {0.f, 0.f, 0.f, 0.f};

    const bf16_t* qrow = q_b + ((size_t)b * T_ + i0 + l15) * C_ + h * HD_;
    bf16x8 qa0 = *(const bf16x8*)(qrow + quad * 8);
    bf16x8 qa1 = *(const bf16x8*)(qrow + 32 + quad * 8);

    const bf16_t* kp[4];
#pragma unroll
    for (int s = 0; s < 4; ++s)
        kp[s] = k_b + ((size_t)b * T_ + wave * 64 + s * 16 + l15) * C_ + h * HD_ + quad * 8;
    const bf16_t* vp[4];
#pragma unroll
    for (int nt = 0; nt < 4; ++nt)
        vp[nt] = vt_g + ((size_t)(b * H_ + h) * HD_ + nt * 16 + l15) * T_ + wave * 64 + quad * 8;
    const float* fp = FF + ((size_t)b * T_ + i0 + l15) * T_ + wave * 64 + quad * 8;

    float m_run = -__builtin_inff(), l_run = 0.f;
    floatx4 O[4];
#pragma unroll
    for (int nt = 0; nt < 4; ++nt) O[nt] = fzero;

#pragma unroll 1
    for (int j0 = wave * 64; j0 <= imax; j0 += 256) {
        // ---- ALL global loads issue first (K, then V^T, then FF) ----
        bf16x8 kb0[4], kb1[4];
#pragma unroll
        for (int s = 0; s < 4; ++s) {
            kb0[s] = *(const bf16x8*)(kp[s]);
            kb1[s] = *(const bf16x8*)(kp[s] + 32);
            kp[s] += 256 * C_;
        }
        bf16x8 vb0[4], vb1[4];
#pragma unroll
        for (int nt = 0; nt < 4; ++nt) {
            vb0[nt] = *(const bf16x8*)(vp[nt]);
            vb1[nt] = *(const bf16x8*)(vp[nt] + 32);
            vp[nt] += 256;
        }
        float ffv[16];
        *(floatx4*)&ffv[0]  = *(const floatx4*)(fp);
        *(floatx4*)&ffv[4]  = *(const floatx4*)(fp + 4);
        *(floatx4*)&ffv[8]  = *(const floatx4*)(fp + 32);
        *(floatx4*)&ffv[12] = *(const floatx4*)(fp + 36);
        fp += 256;

        // QK^T -> C-layout f32 (compiler waits only on K: oldest in vmcnt FIFO)
        floatx4 pc[4];
#pragma unroll
        for (int s = 0; s < 4; ++s) {
            floatx4 p = mfma_bf16(qa0, kb0[s], fzero);
            pc[s] = mfma_bf16(qa1, kb1[s], p);
        }
        // C-layout -> wave-private LDS (raw qk f32)
#pragma unroll
        for (int s = 0; s < 4; ++s)
#pragma unroll
            for (int r = 0; r < 4; ++r)
                LS[wave][quad * 4 + r][s * 16 + l15] = pc[s][r];
        asm volatile("s_waitcnt lgkmcnt(0)" ::: "memory");
        // A-layout read: row=l15, 16 cols (quad*8.. and 32+quad*8..)
        float qk[16];
        *(floatx4*)&qk[0]  = *(const floatx4*)&LS[wave][l15][quad * 8];
        *(floatx4*)&qk[4]  = *(const floatx4*)&LS[wave][l15][quad * 8 + 4];
        *(floatx4*)&qk[8]  = *(const floatx4*)&LS[wave][l15][32 + quad * 8];
        *(floatx4*)&qk[12] = *(const floatx4*)&LS[wave][l15][32 + quad * 8 + 4];

        float lg[16];
#pragma unroll
        for (int c = 0; c < 16; ++c) lg[c] = qk[c] - ffv[c];
        if (j0 + 63 > i0) {   // diagonal chunk only (wave-uniform)
            int i = i0 + l15;
#pragma unroll
            for (int c = 0; c < 16; ++c) {
                int j = j0 + (c >> 3) * 32 + quad * 8 + (c & 7);
                lg[c] = (j <= i) ? lg[c] : -__builtin_inff();
            }
        }
        // online softmax, per-row state scalar per lane (row = l15)
        float rm = lg[0];
#pragma unroll
        for (int c = 1; c < 16; ++c) rm = fmaxf(rm, lg[c]);
        rm = fmaxf(rm, __shfl_xor(rm, 16));
        rm = fmaxf(rm, __shfl_xor(rm, 32));
        float mn = fmaxf(m_run, rm);
        float mnu = fmaxf(mn, -1e30f);       // all-masked-row guard
        float alpha = __expf(m_run - mnu);
        float p[16], ps = 0.f;
#pragma unroll
        for (int c = 0; c < 16; ++c) { p[c] = __expf(lg[c] - mnu); ps += p[c]; }
        ps += __shfl_xor(ps, 16);
        ps += __shfl_xor(ps, 32);
        l_run = l_run * alpha + ps;
        m_run = mn;
        // rescale O (alpha lives at lanes l15=row; O rows = quad*4+r)
#pragma unroll
        for (int r = 0; r < 4; ++r) {
            float ar = __shfl(alpha, quad * 4 + r);
#pragma unroll
            for (int nt = 0; nt < 4; ++nt) O[nt][r] *= ar;
        }
        // P frags in-register (already A-layout); V already resident
        bf16x8 pa0, pa1;
#pragma unroll
        for (int c = 0; c < 8; ++c) { pa0[c] = (bf16_t)p[c]; pa1[c] = (bf16_t)p[8 + c]; }
#pragma unroll
        for (int nt = 0; nt < 4; ++nt) {
            O[nt] = mfma_bf16(pa0, vb0[nt], O[nt]);
            O[nt] = mfma_bf16(pa1, vb1[nt], O[nt]);
        }
    }

    // publish per-wave partials (LS[wave] is wave-private -> no barrier needed)
    if (quad == 0) { Ml[wave][l15][0] = m_run; Ml[wave][l15][1] = l_run; }
#pragma unroll
    for (int r = 0; r < 4; ++r)
#pragma unroll
        for (int nt = 0; nt < 4; ++nt)
            LS[wave][quad * 4 + r][nt * 16 + l15] = O[nt][r];
    __syncthreads();

    // 4-way merge: thread -> (row, 4-col group)
    int row = tid >> 4, cg = tid & 15;
    float mstar = Ml[0][row][0];
#pragma unroll
    for (int w = 1; w < 4; ++w) mstar = fmaxf(mstar, Ml[w][row][0]);
    float aw[4], lsum = 0.f;
#pragma unroll
    for (int w = 0; w < 4; ++w) {
        aw[w] = __expf(Ml[w][row][0] - mstar);
        lsum += aw[w] * Ml[w][row][1];
    }
    float inv = 1.f / lsum;
    union { uint2 u2; bf16_t e[4]; } pk;
#pragma unroll
    for (int c = 0; c < 4; ++c) {
        float o = 0.f;
#pragma unroll
        for (int w = 0; w < 4; ++w) o += aw[w] * LS[w][row][cg * 4 + c];
        pk.e[c] = (bf16_t)(o * inv);
    }
    *(uint2*)(y_b + ((size_t)b * T_ + i0 + row) * C_ + h * HD_ + cg * 4) = pk.u2;
}

// ---------------------------------------------------------------------------
// K7: out = y @ w_proj^T + b_proj  (plain bf16, LDS-staged)
// ---------------------------------------------------------------------------
__global__ __launch_bounds__(256) void proj_gemm(
    const bf16_t* __restrict__ y_b, const bf16_t* __restrict__ wp_b,
    const float* __restrict__ bias, float* __restrict__ out)
{
    extern __shared__ char lds[];
    int m0 = blockIdx.x * 128, n0 = blockIdx.y * 128;
    floatx4 acc[4][4];
#pragma unroll
    for (int i = 0; i < 4; ++i)
#pragma unroll
        for (int j = 0; j < 4; ++j) acc[i][j] = (floatx4){0.f, 0.f, 0.f, 0.f};
    gemm_loop<false>((const char*)(y_b + (size_t)m0 * C_), nullptr,
                     (const char*)(wp_b + (size_t)n0 * C_), nullptr, lds, acc);

    int tid = threadIdx.x, lane = tid & 63, wave = tid >> 6;
    int l15 = lane & 15, quad = lane >> 4;
    int wr = wave >> 1, wc = wave & 1;
#pragma unroll
    for (int ni = 0; ni < 4; ++ni) {
        int col = n0 + wc * 64 + ni * 16 + l15;
        float bb = bias[col];
#pragma unroll
        for (int mi = 0; mi < 4; ++mi)
#pragma unroll
            for (int r = 0; r < 4; ++r)
                out[(size_t)(m0 + wr * 64 + mi * 16 + quad * 4 + r) * C_ + col] =
                    acc[mi][ni][r] + bb;
    }
}

// ---------------------------------------------------------------------------
extern "C" void kernel_launch(void* const* d_in, const int* in_sizes, int n_in,
                              void* d_out, int out_size, void* d_ws, size_t ws_size,
                              hipStream_t stream)
{
    const float* x      = (const float*)d_in[0];
    const float* w_attn = (const float*)d_in[1];
    const float* b_attn = (const float*)d_in[2];
    const float* w_proj = (const float*)d_in[3];
    const float* b_proj = (const float*)d_in[4];
    const float* sel_w  = (const float*)d_in[5];
    float* out = (float*)d_out;

    char* ws = (char*)d_ws;
    size_t off = 0;
    auto alloc = [&](size_t bytes) {
        void* p = ws + off;
        off += (bytes + 255) & ~(size_t)255;
        return p;
    };
    const size_t MC2 = (size_t)M_ * C_ * 2;          // 6.29 MB
    // Persistent region
    bf16_t* q_hi   = (bf16_t*)alloc(MC2);
    bf16_t* q_lo   = (bf16_t*)alloc(MC2);
    bf16_t* kw_hi  = (bf16_t*)alloc(MC2);   // dead after s_gemm -> reused as vt
    bf16_t* kw_lo  = (bf16_t*)alloc(MC2);
    bf16_t* k_b    = (bf16_t*)alloc(MC2);
    bf16_t* v_b    = (bf16_t*)alloc(MC2);
    bf16_t* y_b    = (bf16_t*)alloc(MC2);
    bf16_t* wp_b   = (bf16_t*)alloc((size_t)C_ * C_ * 2);
    float*  segsum = (float*)alloc((size_t)B_ * SEG_ * T_ * 4);
    // Aliased region: phase-1 splits and SF never live simultaneously
    char* shared_base = (char*)alloc((size_t)B_ * T_ * T_ * 4);   // 33.55 MB
    bf16_t* x_hi = (bf16_t*)shared_base;
    bf16_t* x_lo = (bf16_t*)(shared_base + MC2);
    bf16_t* w_hi = (bf16_t*)(shared_base + 2 * MC2);
    bf16_t* w_lo = (bf16_t*)(shared_base + 2 * MC2 + (size_t)N3_ * C_ * 2);
    float*  SF   = (float*)shared_base;
    bf16_t* vt   = kw_hi;   // alias: vt_kernel runs after s_gemm's last read

    int nx = M_ * C_, nw = N3_ * C_, np = C_ * C_;
    split_f32<<<dim3((nx + 255) / 256), 256, 0, stream>>>(x, x_hi, x_lo, nx);
    split_f32<<<dim3((nw + 255) / 256), 256, 0, stream>>>(w_attn, w_hi, w_lo, nw);
    conv_f32<<<dim3((np + 255) / 256), 256, 0, stream>>>(w_proj, wp_b, np);

    qkv_gemm<<<dim3(M_ / 128, N3_ / 128), 256, 32768, stream>>>(
        x_hi, x_lo, w_hi, w_lo, b_attn, sel_w,
        q_hi, q_lo, kw_hi, kw_lo, k_b, v_b);
    s_gemm<<<dim3(T_ / 128, T_ / 128, B_), 256, 32768, stream>>>(
        q_hi, q_lo, kw_hi, kw_lo, SF);
    vt_kernel<<<dim3(T_ / 64, H_, B_), 256, 0, stream>>>(v_b, vt);
    scan_seg_sum<<<dim3(B_ * SEG_ * T_ / 256), 256, 0, stream>>>(SF, segsum);
    scan_seg_excl<<<dim3(B_ * T_ / 256), 256, 0, stream>>>(segsum);
    scan_apply<<<dim3(B_ * SEG_ * T_ / 256), 256, 0, stream>>>(SF, segsum);
    attn_kernel<<<dim3(T_ / 16, H_, B_), 256, 0, stream>>>(q_hi, k_b, vt, SF, y_b);
    proj_gemm<<<dim3(M_ / 128, C_ / 128), 256, 16384, stream>>>(y_b, wp_b, b_proj, out);
}

// Round 8
// 306.502 us; speedup vs baseline: 1.2531x; 1.2531x over previous
//
#include <hip/hip_runtime.h>

#define B_   2
#define T_   2048
#define C_   768
#define H_   12
#define HD_  64
#define M_   (B_ * T_)    // 4096 rows
#define N3_  (3 * C_)     // 2304
#define KB_  (C_ * 2)     // 1536 bytes per row (bf16)

typedef __bf16 bf16_t;
typedef bf16_t bf16x8 __attribute__((ext_vector_type(8)));
typedef float  floatx4 __attribute__((ext_vector_type(4)));

__device__ inline floatx4 mfma_bf16(bf16x8 a, bf16x8 b, floatx4 c) {
    return __builtin_amdgcn_mfma_f32_16x16x32_bf16(a, b, c, 0, 0, 0);
}

__device__ __forceinline__ void async_copy16(const void* g, void* l) {
    __builtin_amdgcn_global_load_lds(
        (const __attribute__((address_space(1))) void*)g,
        (__attribute__((address_space(3))) void*)l, 16, 0, 0);
}

// ---------------------------------------------------------------------------
// Shared 128x128-tile GEMM mainloop.
// ---------------------------------------------------------------------------
__device__ __forceinline__ void stage8k(const char* tile, char* ldsbase,
                                        int k0b, int wave, int lane) {
#pragma unroll
    for (int i = 0; i < 2; ++i) {
        int p = (wave * 2 + i) * 64 + lane;     // 16B slot index 0..511
        int r = p >> 2, slot = p & 3;
        int g = slot ^ ((r >> 1) & 3);
        async_copy16(tile + (size_t)r * KB_ + k0b + g * 16, ldsbase + p * 16);
    }
}

__device__ __forceinline__ bf16x8 frag_read(const char* ldsbase, int row, int quad) {
    int slot = quad ^ ((row >> 1) & 3);
    return *(const bf16x8*)(ldsbase + row * 64 + slot * 16);
}

template<bool TRIPLE>
__device__ __forceinline__ void gemm_loop(
    const char* Ah, const char* Al, const char* Bh, const char* Bl,
    char* lds, floatx4 (&acc)[4][4])
{
    int tid = threadIdx.x, lane = tid & 63, wave = tid >> 6;
    int l15 = lane & 15, quad = lane >> 4;
    int wr = wave >> 1, wc = wave & 1;
    char* LAh = lds;
    char* LAl = lds + 8192;
    char* LBh = lds + (TRIPLE ? 16384 : 8192);
    char* LBl = lds + 24576;
#pragma unroll 1
    for (int k0 = 0; k0 < KB_; k0 += 64) {       // 32 bf16 per chunk
        __syncthreads();
        stage8k(Ah, LAh, k0, wave, lane);
        if (TRIPLE) stage8k(Al, LAl, k0, wave, lane);
        stage8k(Bh, LBh, k0, wave, lane);
        if (TRIPLE) stage8k(Bl, LBl, k0, wave, lane);
        __syncthreads();
        bf16x8 ah[4], al[4], bh[4], bl[4];
#pragma unroll
        for (int t = 0; t < 4; ++t) {
            ah[t] = frag_read(LAh, wr * 64 + t * 16 + l15, quad);
            bh[t] = frag_read(LBh, wc * 64 + t * 16 + l15, quad);
            if (TRIPLE) {
                al[t] = frag_read(LAl, wr * 64 + t * 16 + l15, quad);
                bl[t] = frag_read(LBl, wc * 64 + t * 16 + l15, quad);
            }
        }
#pragma unroll
        for (int mi = 0; mi < 4; ++mi)
#pragma unroll
            for (int ni = 0; ni < 4; ++ni) {
                acc[mi][ni] = mfma_bf16(ah[mi], bh[ni], acc[mi][ni]);
                if (TRIPLE) {
                    acc[mi][ni] = mfma_bf16(ah[mi], bl[ni], acc[mi][ni]);
                    acc[mi][ni] = mfma_bf16(al[mi], bh[ni], acc[mi][ni]);
                }
            }
    }
}

// ---------------------------------------------------------------------------
// K0: fp32 -> bf16 hi/lo split (and plain convert)
// ---------------------------------------------------------------------------
__global__ __launch_bounds__(256) void split_f32(
    const float* __restrict__ src, bf16_t* __restrict__ hi,
    bf16_t* __restrict__ lo, int n)
{
    int i = blockIdx.x * 256 + threadIdx.x;
    if (i < n) {
        float f = src[i];
        bf16_t h = (bf16_t)f;
        hi[i] = h;
        lo[i] = (bf16_t)(f - (float)h);
    }
}

__global__ __launch_bounds__(256) void conv_f32(
    const float* __restrict__ src, bf16_t* __restrict__ dst, int n)
{
    int i = blockIdx.x * 256 + threadIdx.x;
    if (i < n) dst[i] = (bf16_t)src[i];
}

// ---------------------------------------------------------------------------
// K1: qkv = x @ w_attn^T + b_attn.  q/k sections bf16x3; v section bf16.
// q stored PRE-SCALED by 0.125.
// ---------------------------------------------------------------------------
__global__ __launch_bounds__(256) void qkv_gemm(
    const bf16_t* __restrict__ x_hi, const bf16_t* __restrict__ x_lo,
    const bf16_t* __restrict__ w_hi, const bf16_t* __restrict__ w_lo,
    const float* __restrict__ bias, const float* __restrict__ selw,
    bf16_t* __restrict__ q_hi, bf16_t* __restrict__ q_lo,
    bf16_t* __restrict__ kw_hi, bf16_t* __restrict__ kw_lo,
    bf16_t* __restrict__ k_b, bf16_t* __restrict__ v_b)
{
    extern __shared__ char lds[];
    int m0 = blockIdx.x * 128, n0 = blockIdx.y * 128;
    floatx4 acc[4][4];
#pragma unroll
    for (int i = 0; i < 4; ++i)
#pragma unroll
        for (int j = 0; j < 4; ++j) acc[i][j] = (floatx4){0.f, 0.f, 0.f, 0.f};
    if (n0 >= 2 * C_) {   // v section: single-precision bf16 path
        gemm_loop<false>((const char*)(x_hi + (size_t)m0 * C_), nullptr,
                         (const char*)(w_hi + (size_t)n0 * C_), nullptr, lds, acc);
    } else {
        gemm_loop<true>((const char*)(x_hi + (size_t)m0 * C_),
                        (const char*)(x_lo + (size_t)m0 * C_),
                        (const char*)(w_hi + (size_t)n0 * C_),
                        (const char*)(w_lo + (size_t)n0 * C_), lds, acc);
    }

    int tid = threadIdx.x, lane = tid & 63, wave = tid >> 6;
    int l15 = lane & 15, quad = lane >> 4;
    int wr = wave >> 1, wc = wave & 1;
    int cb = n0 + wc * 64;   // wave-uniform: section (q/k/v) is uniform
#pragma unroll
    for (int ni = 0; ni < 4; ++ni) {
        int col = cb + ni * 16 + l15;
        float bb = bias[col];
#pragma unroll
        for (int mi = 0; mi < 4; ++mi)
#pragma unroll
            for (int r = 0; r < 4; ++r) {
                int row = m0 + wr * 64 + mi * 16 + quad * 4 + r;
                float v = acc[mi][ni][r] + bb;
                if (cb < C_) {
                    float vs = v * 0.125f;           // fold softmax scale
                    bf16_t h = (bf16_t)vs;
                    q_hi[(size_t)row * C_ + col] = h;
                    q_lo[(size_t)row * C_ + col] = (bf16_t)(vs - (float)h);
                } else if (cb < 2 * C_) {
                    int c2 = col - C_;
                    k_b[(size_t)row * C_ + c2] = (bf16_t)v;
                    float kw = v * selw[c2 >> 6];
                    bf16_t h = (bf16_t)kw;
                    kw_hi[(size_t)row * C_ + c2] = h;
                    kw_lo[(size_t)row * C_ + c2] = (bf16_t)(kw - (float)h);
                } else {
                    v_b[(size_t)row * C_ + (col - 2 * C_)] = (bf16_t)v;
                }
            }
    }
}

// ---------------------------------------------------------------------------
// K2: S[b,i,j] = (1<=j<i) ? relu(q_i . kw_j) : 0   (bf16x3; 0.125 pre-folded)
// ---------------------------------------------------------------------------
__global__ __launch_bounds__(256) void s_gemm(
    const bf16_t* __restrict__ q_hi, const bf16_t* __restrict__ q_lo,
    const bf16_t* __restrict__ kw_hi, const bf16_t* __restrict__ kw_lo,
    float* __restrict__ SF)
{
    extern __shared__ char lds[];
    int i0 = blockIdx.x * 128, j0 = blockIdx.y * 128, b = blockIdx.z;
    float* out = SF + (size_t)b * T_ * T_;
    int tid = threadIdx.x;
    if (j0 > i0) {   // fully-masked tile: zero-fill (scan needs init'd buffer)
        float4 z = {0.f, 0.f, 0.f, 0.f};
        float* p = out + (size_t)(i0 + (tid >> 1)) * T_ + j0 + (tid & 1) * 64;
#pragma unroll
        for (int c = 0; c < 16; ++c) ((float4*)p)[c] = z;
        return;
    }
    floatx4 acc[4][4];
#pragma unroll
    for (int i = 0; i < 4; ++i)
#pragma unroll
        for (int j = 0; j < 4; ++j) acc[i][j] = (floatx4){0.f, 0.f, 0.f, 0.f};
    size_t arow = ((size_t)b * T_ + i0) * C_;
    size_t brow = ((size_t)b * T_ + j0) * C_;
    gemm_loop<true>((const char*)(q_hi + arow), (const char*)(q_lo + arow),
                    (const char*)(kw_hi + brow), (const char*)(kw_lo + brow),
                    lds, acc);

    int lane = tid & 63, wave = tid >> 6;
    int l15 = lane & 15, quad = lane >> 4;
    int wr = wave >> 1, wc = wave & 1;
#pragma unroll
    for (int ni = 0; ni < 4; ++ni) {
        int j = j0 + wc * 64 + ni * 16 + l15;
#pragma unroll
        for (int mi = 0; mi < 4; ++mi)
#pragma unroll
            for (int r = 0; r < 4; ++r) {
                int i = i0 + wr * 64 + mi * 16 + quad * 4 + r;
                float s = acc[mi][ni][r];
                s = (j >= 1 && j < i) ? fmaxf(s, 0.f) : 0.f;
                out[(size_t)i * T_ + j] = s;
            }
    }
}

// ---------------------------------------------------------------------------
// K3-K5: per-column exclusive prefix sum over rows (FF_shifted), 3-phase.
// ---------------------------------------------------------------------------
#define SEG_    16
#define SEGLEN_ (T_ / SEG_)  // 128

__global__ __launch_bounds__(256) void scan_seg_sum(
    const float* __restrict__ SF, float* __restrict__ segsum)
{
    int gid  = blockIdx.x * 256 + threadIdx.x;
    int j    = gid & (T_ - 1);
    int rest = gid >> 11;
    int seg  = rest & (SEG_ - 1);
    int b    = rest >> 4;
    const float* col = SF + (size_t)b * T_ * T_ + (size_t)(seg * SEGLEN_) * T_ + j;
    float s = 0.f;
#pragma unroll 8
    for (int i = 0; i < SEGLEN_; ++i) s += col[(size_t)i * T_];
    segsum[((size_t)b * SEG_ + seg) * T_ + j] = s;
}

__global__ __launch_bounds__(256) void scan_seg_excl(float* __restrict__ segsum)
{
    int gid = blockIdx.x * 256 + threadIdx.x;
    int j = gid & (T_ - 1);
    int b = gid >> 11;
    float run = 0.f;
#pragma unroll
    for (int s = 0; s < SEG_; ++s) {
        size_t idx = ((size_t)b * SEG_ + s) * T_ + j;
        float v = segsum[idx];
        segsum[idx] = run;
        run += v;
    }
}

__global__ __launch_bounds__(256) void scan_apply(
    float* __restrict__ SF, const float* __restrict__ segsum)
{
    int gid  = blockIdx.x * 256 + threadIdx.x;
    int j    = gid & (T_ - 1);
    int rest = gid >> 11;
    int seg  = rest & (SEG_ - 1);
    int b    = rest >> 4;
    float run = segsum[((size_t)b * SEG_ + seg) * T_ + j];
    float* col = SF + (size_t)b * T_ * T_ + (size_t)(seg * SEGLEN_) * T_ + j;
#pragma unroll 4
    for (int i = 0; i < SEGLEN_; ++i) {
        float s = col[(size_t)i * T_];
        col[(size_t)i * T_] = run;   // exclusive: FF_shifted[i,j]
        run += s;
    }
}

// ---------------------------------------------------------------------------
// K5b: V -> V^T  (per (b,h): [T][64] -> [64][T]).
// ---------------------------------------------------------------------------
__global__ __launch_bounds__(256) void vt_kernel(
    const bf16_t* __restrict__ v_b, bf16_t* __restrict__ vt)
{
    __shared__ bf16_t tile[64][72];
    int t0 = blockIdx.x * 64, h = blockIdx.y, b = blockIdx.z;
    int tid = threadIdx.x;
    int r = tid >> 2, sl = tid & 3;           // r: 0..63, sl: 0..3 (16 elems each)
    const bf16_t* src = v_b + ((size_t)(b * T_ + t0 + r)) * C_ + h * HD_ + sl * 16;
    *(int4*)&tile[r][sl * 16]     = *(const int4*)src;
    *(int4*)&tile[r][sl * 16 + 8] = *(const int4*)(src + 8);
    __syncthreads();
    int hd = tid >> 2, q = tid & 3;
#pragma unroll
    for (int half = 0; half < 2; ++half) {
        int c0 = (q * 2 + half) * 8;
        union { int4 i4; bf16_t e[8]; } u;
#pragma unroll
        for (int kk = 0; kk < 8; ++kk) u.e[kk] = tile[c0 + kk][hd];
        *(int4*)(vt + ((size_t)(b * H_ + h) * HD_ + hd) * T_ + t0 + c0) = u.i4;
    }
}

// ---------------------------------------------------------------------------
// K6 (v6): double-buffered LDS flash attention (m97-style).
// Block = (b, h, 64 i-rows); 4 waves share each 64-col j-chunk.  K-tile and
// V^T-tile staged via global_load_lds (async, zero VGPR cost) into XOR-
// swizzled LDS (2-way aliasing only = free), double-buffered: stage(j+1)
// issues right after the barrier and overlaps all of compute(j).  ONE
// barrier per iteration.  Register-resident prefetch abandoned (round-7
// post-mortem: compiler sinks loads / spills).  A-layout softmax from v4.
// Each wave owns its 16 rows end-to-end: no merge epilogue.
// LDS 50 KB -> 3 blocks/CU; heavy-first block order balances the causal load.
// ---------------------------------------------------------------------------
__global__ __launch_bounds__(256) void attn_kernel(
    const bf16_t* __restrict__ q_b, const bf16_t* __restrict__ k_b,
    const bf16_t* __restrict__ vt_g, const float* __restrict__ FF,
    bf16_t* __restrict__ y_b)
{
    __shared__ __align__(16) char KL[2][8192];      // K tile: 64 j-rows x 128B
    __shared__ __align__(16) char VL[2][8192];      // V^T tile: 64 hd-rows x 128B
    __shared__ __align__(16) float LS[4][16][68];   // per-wave qk roundtrip

    int tid = threadIdx.x, lane = tid & 63, wave = tid >> 6;
    int l15 = lane & 15, quad = lane >> 4;
    int bi = (int)gridDim.x - 1 - (int)blockIdx.x;  // heavy-first
    int h = blockIdx.y, b = blockIdx.z;
    int i0w = bi * 64 + wave * 16;                  // this wave's 16 rows
    int jmax = bi * 64 + 63;
    const floatx4 fzero = {0.f, 0.f, 0.f, 0.f};

    // Q fragments (A-layout), once
    const bf16_t* qrow = q_b + ((size_t)b * T_ + i0w + l15) * C_ + h * HD_;
    bf16x8 qa0 = *(const bf16x8*)(qrow + quad * 8);
    bf16x8 qa1 = *(const bf16x8*)(qrow + 32 + quad * 8);

    const bf16_t* kbase = k_b + (size_t)b * T_ * C_ + h * HD_;
    const bf16_t* vbase = vt_g + (size_t)(b * H_ + h) * HD_ * T_;
    const float*  fp    = FF + ((size_t)b * T_ + i0w + l15) * T_ + quad * 8;

    // async stage of one 64-col chunk: K rows j0..j0+63 (128B each) and
    // V^T rows hd 0..63 (cols j0..j0+63).  XOR-swizzle slot s' = s ^ (r&7).
    auto stage = [&](int ph, int j0) {
#pragma unroll
        for (int i = 0; i < 2; ++i) {
            int p = (wave * 2 + i) * 64 + lane;     // 0..511
            int r = p >> 3, sp = p & 7, s = sp ^ (r & 7);
            async_copy16(kbase + (size_t)(j0 + r) * C_ + s * 8, &KL[ph][p * 16]);
        }
#pragma unroll
        for (int i = 0; i < 2; ++i) {
            int p = (wave * 2 + i) * 64 + lane;
            int r = p >> 3, sp = p & 7, s = sp ^ (r & 7);
            async_copy16(vbase + (size_t)r * T_ + j0 + s * 8, &VL[ph][p * 16]);
        }
    };

    float m_run = -__builtin_inff(), l_run = 0.f;
    floatx4 O[4];
#pragma unroll
    for (int nt = 0; nt < 4; ++nt) O[nt] = fzero;

    stage(0, 0);
    int ph = 0;
#pragma unroll 1
    for (int j0 = 0; j0 <= jmax; j0 += 64) {
        __syncthreads();                            // staged data visible
        if (j0 + 64 <= jmax) stage(ph ^ 1, j0 + 64);

        // FF loads (the only per-wave VMEM in the loop)
        float ffv[16];
        *(floatx4*)&ffv[0]  = *(const floatx4*)(fp);
        *(floatx4*)&ffv[4]  = *(const floatx4*)(fp + 4);
        *(floatx4*)&ffv[8]  = *(const floatx4*)(fp + 32);
        *(floatx4*)&ffv[12] = *(const floatx4*)(fp + 36);
        fp += 64;

        // QK^T from KL[ph]
        floatx4 pc[4];
#pragma unroll
        for (int s = 0; s < 4; ++s) {
            int r = s * 16 + l15;
            bf16x8 k0 = *(const bf16x8*)&KL[ph][r * 128 + ((quad     ^ (r & 7)) * 16)];
            bf16x8 k1 = *(const bf16x8*)&KL[ph][r * 128 + (((quad+4) ^ (r & 7)) * 16)];
            floatx4 p = mfma_bf16(qa0, k0, fzero);
            pc[s] = mfma_bf16(qa1, k1, p);
        }
        // C-layout -> wave-private LDS -> A-layout
#pragma unroll
        for (int s = 0; s < 4; ++s)
#pragma unroll
            for (int r = 0; r < 4; ++r)
                LS[wave][quad * 4 + r][s * 16 + l15] = pc[s][r];
        float qk[16];
        *(floatx4*)&qk[0]  = *(const floatx4*)&LS[wave][l15][quad * 8];
        *(floatx4*)&qk[4]  = *(const floatx4*)&LS[wave][l15][quad * 8 + 4];
        *(floatx4*)&qk[8]  = *(const floatx4*)&LS[wave][l15][32 + quad * 8];
        *(floatx4*)&qk[12] = *(const floatx4*)&LS[wave][l15][32 + quad * 8 + 4];

        float lg[16];
#pragma unroll
        for (int c = 0; c < 16; ++c) lg[c] = qk[c] - ffv[c];
        if (j0 + 63 > i0w) {   // diagonal chunk only (wave-uniform)
            int i = i0w + l15;
#pragma unroll
            for (int c = 0; c < 16; ++c) {
                int j = j0 + (c >> 3) * 32 + quad * 8 + (c & 7);
                lg[c] = (j <= i) ? lg[c] : -__builtin_inff();
            }
        }
        // online softmax (row = l15; lanes {q*16+l15} hold copies)
        float rm = lg[0];
#pragma unroll
        for (int c = 1; c < 16; ++c) rm = fmaxf(rm, lg[c]);
        rm = fmaxf(rm, __shfl_xor(rm, 16));
        rm = fmaxf(rm, __shfl_xor(rm, 32));
        float mn = fmaxf(m_run, rm);
        float mnu = fmaxf(mn, -1e30f);
        float alpha = __expf(m_run - mnu);
        float p[16], ps = 0.f;
#pragma unroll
        for (int c = 0; c < 16; ++c) { p[c] = __expf(lg[c] - mnu); ps += p[c]; }
        ps += __shfl_xor(ps, 16);
        ps += __shfl_xor(ps, 32);
        l_run = l_run * alpha + ps;
        m_run = mn;
        // rescale O (O rows = quad*4+r in C-layout)
#pragma unroll
        for (int r = 0; r < 4; ++r) {
            float ar = __shfl(alpha, quad * 4 + r);
#pragma unroll
            for (int nt = 0; nt < 4; ++nt) O[nt][r] *= ar;
        }
        // P frags (already A-layout) and PV from VL[ph]
        bf16x8 pa0, pa1;
#pragma unroll
        for (int c = 0; c < 8; ++c) { pa0[c] = (bf16_t)p[c]; pa1[c] = (bf16_t)p[8 + c]; }
#pragma unroll
        for (int nt = 0; nt < 4; ++nt) {
            int r = nt * 16 + l15;
            bf16x8 v0 = *(const bf16x8*)&VL[ph][r * 128 + ((quad     ^ (r & 7)) * 16)];
            bf16x8 v1 = *(const bf16x8*)&VL[ph][r * 128 + (((quad+4) ^ (r & 7)) * 16)];
            O[nt] = mfma_bf16(pa0, v0, O[nt]);
            O[nt] = mfma_bf16(pa1, v1, O[nt]);
        }
        ph ^= 1;
    }

    // epilogue: each wave writes its own 16 rows
#pragma unroll
    for (int r = 0; r < 4; ++r) {
        float inv = 1.f / __shfl(l_run, quad * 4 + r);
        int i = i0w + quad * 4 + r;
#pragma unroll
        for (int nt = 0; nt < 4; ++nt)
            y_b[((size_t)b * T_ + i) * C_ + h * HD_ + nt * 16 + l15] =
                (bf16_t)(O[nt][r] * inv);
    }
}

// ---------------------------------------------------------------------------
// K7: out = y @ w_proj^T + b_proj  (plain bf16, LDS-staged)
// ---------------------------------------------------------------------------
__global__ __launch_bounds__(256) void proj_gemm(
    const bf16_t* __restrict__ y_b, const bf16_t* __restrict__ wp_b,
    const float* __restrict__ bias, float* __restrict__ out)
{
    extern __shared__ char lds[];
    int m0 = blockIdx.x * 128, n0 = blockIdx.y * 128;
    floatx4 acc[4][4];
#pragma unroll
    for (int i = 0; i < 4; ++i)
#pragma unroll
        for (int j = 0; j < 4; ++j) acc[i][j] = (floatx4){0.f, 0.f, 0.f, 0.f};
    gemm_loop<false>((const char*)(y_b + (size_t)m0 * C_), nullptr,
                     (const char*)(wp_b + (size_t)n0 * C_), nullptr, lds, acc);

    int tid = threadIdx.x, lane = tid & 63, wave = tid >> 6;
    int l15 = lane & 15, quad = lane >> 4;
    int wr = wave >> 1, wc = wave & 1;
#pragma unroll
    for (int ni = 0; ni < 4; ++ni) {
        int col = n0 + wc * 64 + ni * 16 + l15;
        float bb = bias[col];
#pragma unroll
        for (int mi = 0; mi < 4; ++mi)
#pragma unroll
            for (int r = 0; r < 4; ++r)
                out[(size_t)(m0 + wr * 64 + mi * 16 + quad * 4 + r) * C_ + col] =
                    acc[mi][ni][r] + bb;
    }
}

// ---------------------------------------------------------------------------
extern "C" void kernel_launch(void* const* d_in, const int* in_sizes, int n_in,
                              void* d_out, int out_size, void* d_ws, size_t ws_size,
                              hipStream_t stream)
{
    const float* x      = (const float*)d_in[0];
    const float* w_attn = (const float*)d_in[1];
    const float* b_attn = (const float*)d_in[2];
    const float* w_proj = (const float*)d_in[3];
    const float* b_proj = (const float*)d_in[4];
    const float* sel_w  = (const float*)d_in[5];
    float* out = (float*)d_out;

    char* ws = (char*)d_ws;
    size_t off = 0;
    auto alloc = [&](size_t bytes) {
        void* p = ws + off;
        off += (bytes + 255) & ~(size_t)255;
        return p;
    };
    const size_t MC2 = (size_t)M_ * C_ * 2;          // 6.29 MB
    // Persistent region
    bf16_t* q_hi   = (bf16_t*)alloc(MC2);
    bf16_t* q_lo   = (bf16_t*)alloc(MC2);
    bf16_t* kw_hi  = (bf16_t*)alloc(MC2);   // dead after s_gemm -> reused as vt
    bf16_t* kw_lo  = (bf16_t*)alloc(MC2);
    bf16_t* k_b    = (bf16_t*)alloc(MC2);
    bf16_t* v_b    = (bf16_t*)alloc(MC2);
    bf16_t* y_b    = (bf16_t*)alloc(MC2);
    bf16_t* wp_b   = (bf16_t*)alloc((size_t)C_ * C_ * 2);
    float*  segsum = (float*)alloc((size_t)B_ * SEG_ * T_ * 4);
    // Aliased region: phase-1 splits and SF never live simultaneously
    char* shared_base = (char*)alloc((size_t)B_ * T_ * T_ * 4);   // 33.55 MB
    bf16_t* x_hi = (bf16_t*)shared_base;
    bf16_t* x_lo = (bf16_t*)(shared_base + MC2);
    bf16_t* w_hi = (bf16_t*)(shared_base + 2 * MC2);
    bf16_t* w_lo = (bf16_t*)(shared_base + 2 * MC2 + (size_t)N3_ * C_ * 2);
    float*  SF   = (float*)shared_base;
    bf16_t* vt   = kw_hi;   // alias: vt_kernel runs after s_gemm's last read

    int nx = M_ * C_, nw = N3_ * C_, np = C_ * C_;
    split_f32<<<dim3((nx + 255) / 256), 256, 0, stream>>>(x, x_hi, x_lo, nx);
    split_f32<<<dim3((nw + 255) / 256), 256, 0, stream>>>(w_attn, w_hi, w_lo, nw);
    conv_f32<<<dim3((np + 255) / 256), 256, 0, stream>>>(w_proj, wp_b, np);

    qkv_gemm<<<dim3(M_ / 128, N3_ / 128), 256, 32768, stream>>>(
        x_hi, x_lo, w_hi, w_lo, b_attn, sel_w,
        q_hi, q_lo, kw_hi, kw_lo, k_b, v_b);
    s_gemm<<<dim3(T_ / 128, T_ / 128, B_), 256, 32768, stream>>>(
        q_hi, q_lo, kw_hi, kw_lo, SF);
    vt_kernel<<<dim3(T_ / 64, H_, B_), 256, 0, stream>>>(v_b, vt);
    scan_seg_sum<<<dim3(B_ * SEG_ * T_ / 256), 256, 0, stream>>>(SF, segsum);
    scan_seg_excl<<<dim3(B_ * T_ / 256), 256, 0, stream>>>(segsum);
    scan_apply<<<dim3(B_ * SEG_ * T_ / 256), 256, 0, stream>>>(SF, segsum);
    attn_kernel<<<dim3(T_ / 64, H_, B_), 256, 0, stream>>>(q_hi, k_b, vt, SF, y_b);
    proj_gemm<<<dim3(M_ / 128, C_ / 128), 256, 16384, stream>>>(y_b, wp_b, b_proj, out);
}

// Round 10
// 282.073 us; speedup vs baseline: 1.3616x; 1.0866x over previous
//
#include <hip/hip_runtime.h>

#define B_   2
#define T_   2048
#define C_   768
#define H_   12
#define HD_  64
#define M_   (B_ * T_)    // 4096 rows
#define N3_  (3 * C_)     // 2304
#define KB_  (C_ * 2)     // 1536 bytes per row (bf16)

typedef __bf16 bf16_t;
typedef bf16_t bf16x8 __attribute__((ext_vector_type(8)));
typedef float  floatx4 __attribute__((ext_vector_type(4)));

__device__ inline floatx4 mfma_bf16(bf16x8 a, bf16x8 b, floatx4 c) {
    return __builtin_amdgcn_mfma_f32_16x16x32_bf16(a, b, c, 0, 0, 0);
}

__device__ __forceinline__ void async_copy16(const void* g, void* l) {
    __builtin_amdgcn_global_load_lds(
        (const __attribute__((address_space(1))) void*)g,
        (__attribute__((address_space(3))) void*)l, 16, 0, 0);
}

// ---------------------------------------------------------------------------
// Shared 128x128-tile GEMM mainloop, DOUBLE-BUFFERED.
// barrier -> stage(k+1) -> compute(k); staging latency overlaps compute.
// Phase = 32 KB (triple) / 16 KB (single).  NOTE: launch LDS must be 2*PH.
// ---------------------------------------------------------------------------
__device__ __forceinline__ void stage8k(const char* tile, char* ldsbase,
                                        int k0b, int wave, int lane) {
#pragma unroll
    for (int i = 0; i < 2; ++i) {
        int p = (wave * 2 + i) * 64 + lane;     // 16B slot index 0..511
        int r = p >> 2, slot = p & 3;
        int g = slot ^ ((r >> 1) & 3);
        async_copy16(tile + (size_t)r * KB_ + k0b + g * 16, ldsbase + p * 16);
    }
}

__device__ __forceinline__ bf16x8 frag_read(const char* ldsbase, int row, int quad) {
    int slot = quad ^ ((row >> 1) & 3);
    return *(const bf16x8*)(ldsbase + row * 64 + slot * 16);
}

template<bool TRIPLE>
__device__ __forceinline__ void gemm_loop(
    const char* Ah, const char* Al, const char* Bh, const char* Bl,
    char* lds, floatx4 (&acc)[4][4])
{
    int tid = threadIdx.x, lane = tid & 63, wave = tid >> 6;
    int l15 = lane & 15, quad = lane >> 4;
    int wr = wave >> 1, wc = wave & 1;
    const int PH = TRIPLE ? 32768 : 16384;
    auto stage = [&](int ph, int k0) {
        char* base = lds + ph * PH;
        stage8k(Ah, base, k0, wave, lane);
        stage8k(Bh, base + 8192, k0, wave, lane);
        if (TRIPLE) {
            stage8k(Al, base + 16384, k0, wave, lane);
            stage8k(Bl, base + 24576, k0, wave, lane);
        }
    };
    stage(0, 0);
    int ph = 0;
#pragma unroll 1
    for (int k0 = 0; k0 < KB_; k0 += 64) {       // 32 bf16 per chunk
        __syncthreads();                          // drains stage(ph)
        if (k0 + 64 < KB_) stage(ph ^ 1, k0 + 64);
        char* base = lds + ph * PH;
        bf16x8 ah[4], al[4], bh[4], bl[4];
#pragma unroll
        for (int t = 0; t < 4; ++t) {
            ah[t] = frag_read(base,         wr * 64 + t * 16 + l15, quad);
            bh[t] = frag_read(base + 8192,  wc * 64 + t * 16 + l15, quad);
            if (TRIPLE) {
                al[t] = frag_read(base + 16384, wr * 64 + t * 16 + l15, quad);
                bl[t] = frag_read(base + 24576, wc * 64 + t * 16 + l15, quad);
            }
        }
#pragma unroll
        for (int mi = 0; mi < 4; ++mi)
#pragma unroll
            for (int ni = 0; ni < 4; ++ni) {
                acc[mi][ni] = mfma_bf16(ah[mi], bh[ni], acc[mi][ni]);
                if (TRIPLE) {
                    acc[mi][ni] = mfma_bf16(ah[mi], bl[ni], acc[mi][ni]);
                    acc[mi][ni] = mfma_bf16(al[mi], bh[ni], acc[mi][ni]);
                }
            }
        ph ^= 1;
    }
}

// ---------------------------------------------------------------------------
// K0: fp32 -> bf16 hi/lo split (and plain convert)
// ---------------------------------------------------------------------------
__global__ __launch_bounds__(256) void split_f32(
    const float* __restrict__ src, bf16_t* __restrict__ hi,
    bf16_t* __restrict__ lo, int n)
{
    int i = blockIdx.x * 256 + threadIdx.x;
    if (i < n) {
        float f = src[i];
        bf16_t h = (bf16_t)f;
        hi[i] = h;
        lo[i] = (bf16_t)(f - (float)h);
    }
}

__global__ __launch_bounds__(256) void conv_f32(
    const float* __restrict__ src, bf16_t* __restrict__ dst, int n)
{
    int i = blockIdx.x * 256 + threadIdx.x;
    if (i < n) dst[i] = (bf16_t)src[i];
}

// ---------------------------------------------------------------------------
// K1: qkv = x @ w_attn^T + b_attn.  q/k sections bf16x3; v section bf16.
// q stored PRE-SCALED by 0.125.
// ---------------------------------------------------------------------------
__global__ __launch_bounds__(256) void qkv_gemm(
    const bf16_t* __restrict__ x_hi, const bf16_t* __restrict__ x_lo,
    const bf16_t* __restrict__ w_hi, const bf16_t* __restrict__ w_lo,
    const float* __restrict__ bias, const float* __restrict__ selw,
    bf16_t* __restrict__ q_hi, bf16_t* __restrict__ q_lo,
    bf16_t* __restrict__ kw_hi, bf16_t* __restrict__ kw_lo,
    bf16_t* __restrict__ k_b, bf16_t* __restrict__ v_b)
{
    extern __shared__ char lds[];
    int m0 = blockIdx.x * 128, n0 = blockIdx.y * 128;
    floatx4 acc[4][4];
#pragma unroll
    for (int i = 0; i < 4; ++i)
#pragma unroll
        for (int j = 0; j < 4; ++j) acc[i][j] = (floatx4){0.f, 0.f, 0.f, 0.f};
    if (n0 >= 2 * C_) {   // v section: single-precision bf16 path
        gemm_loop<false>((const char*)(x_hi + (size_t)m0 * C_), nullptr,
                         (const char*)(w_hi + (size_t)n0 * C_), nullptr, lds, acc);
    } else {
        gemm_loop<true>((const char*)(x_hi + (size_t)m0 * C_),
                        (const char*)(x_lo + (size_t)m0 * C_),
                        (const char*)(w_hi + (size_t)n0 * C_),
                        (const char*)(w_lo + (size_t)n0 * C_), lds, acc);
    }

    int tid = threadIdx.x, lane = tid & 63, wave = tid >> 6;
    int l15 = lane & 15, quad = lane >> 4;
    int wr = wave >> 1, wc = wave & 1;
    int cb = n0 + wc * 64;   // wave-uniform: section (q/k/v) is uniform
#pragma unroll
    for (int ni = 0; ni < 4; ++ni) {
        int col = cb + ni * 16 + l15;
        float bb = bias[col];
#pragma unroll
        for (int mi = 0; mi < 4; ++mi)
#pragma unroll
            for (int r = 0; r < 4; ++r) {
                int row = m0 + wr * 64 + mi * 16 + quad * 4 + r;
                float v = acc[mi][ni][r] + bb;
                if (cb < C_) {
                    float vs = v * 0.125f;           // fold softmax scale
                    bf16_t h = (bf16_t)vs;
                    q_hi[(size_t)row * C_ + col] = h;
                    q_lo[(size_t)row * C_ + col] = (bf16_t)(vs - (float)h);
                } else if (cb < 2 * C_) {
                    int c2 = col - C_;
                    k_b[(size_t)row * C_ + c2] = (bf16_t)v;
                    float kw = v * selw[c2 >> 6];
                    bf16_t h = (bf16_t)kw;
                    kw_hi[(size_t)row * C_ + c2] = h;
                    kw_lo[(size_t)row * C_ + c2] = (bf16_t)(kw - (float)h);
                } else {
                    v_b[(size_t)row * C_ + (col - 2 * C_)] = (bf16_t)v;
                }
            }
    }
}

// ---------------------------------------------------------------------------
// K2: triangular s_gemm, lower-triangle tiles only (136/batch), fused segsum.
// ---------------------------------------------------------------------------
#define SEG_    16
#define SEGLEN_ (T_ / SEG_)  // 128

__global__ __launch_bounds__(256) void s_gemm(
    const bf16_t* __restrict__ q_hi, const bf16_t* __restrict__ q_lo,
    const bf16_t* __restrict__ kw_hi, const bf16_t* __restrict__ kw_lo,
    float* __restrict__ SF, float* __restrict__ segsum)
{
    extern __shared__ char lds[];
    int t = blockIdx.x, b = blockIdx.z;
    int it = (int)((sqrtf(8.f * t + 1.f) - 1.f) * 0.5f);
    while ((it + 1) * (it + 2) / 2 <= t) ++it;
    while (it * (it + 1) / 2 > t) --it;
    int jt = t - it * (it + 1) / 2;               // jt <= it
    int i0 = it * 128, j0 = jt * 128;
    float* out = SF + (size_t)b * T_ * T_;

    floatx4 acc[4][4];
#pragma unroll
    for (int i = 0; i < 4; ++i)
#pragma unroll
        for (int j = 0; j < 4; ++j) acc[i][j] = (floatx4){0.f, 0.f, 0.f, 0.f};
    size_t arow = ((size_t)b * T_ + i0) * C_;
    size_t brow = ((size_t)b * T_ + j0) * C_;
    gemm_loop<true>((const char*)(q_hi + arow), (const char*)(q_lo + arow),
                    (const char*)(kw_hi + brow), (const char*)(kw_lo + brow),
                    lds, acc);

    int tid = threadIdx.x, lane = tid & 63, wave = tid >> 6;
    int l15 = lane & 15, quad = lane >> 4;
    int wr = wave >> 1, wc = wave & 1;
    float colsum[4] = {0.f, 0.f, 0.f, 0.f};
#pragma unroll
    for (int ni = 0; ni < 4; ++ni) {
        int j = j0 + wc * 64 + ni * 16 + l15;
#pragma unroll
        for (int mi = 0; mi < 4; ++mi)
#pragma unroll
            for (int r = 0; r < 4; ++r) {
                int i = i0 + wr * 64 + mi * 16 + quad * 4 + r;
                float s = acc[mi][ni][r];
                s = (j >= 1 && j < i) ? fmaxf(s, 0.f) : 0.f;
                out[(size_t)i * T_ + j] = s;
                colsum[ni] += s;
            }
    }
    // reduce across quads (rows); column = wc*64+ni*16+l15 is quad-invariant
#pragma unroll
    for (int ni = 0; ni < 4; ++ni) {
        colsum[ni] += __shfl_xor(colsum[ni], 16);
        colsum[ni] += __shfl_xor(colsum[ni], 32);
    }
    float* red = (float*)lds;                     // [wr][wc][64] (phase-0 area)
    if (quad == 0) {
#pragma unroll
        for (int ni = 0; ni < 4; ++ni)
            red[wr * 128 + wc * 64 + ni * 16 + l15] = colsum[ni];
    }
    __syncthreads();
    if (wave < 2) {   // wave 0/1: wc = wave column group
        float ssum = red[wave * 64 + lane] + red[128 + wave * 64 + lane];
        segsum[((size_t)b * SEG_ + it) * T_ + j0 + wave * 64 + lane] = ssum;
    }
}

// ---------------------------------------------------------------------------
// K4-K5: column scan with triangle predicates.
// ---------------------------------------------------------------------------
__global__ __launch_bounds__(256) void scan_seg_excl(float* __restrict__ segsum)
{
    int gid = blockIdx.x * 256 + threadIdx.x;
    int j = gid & (T_ - 1);
    int b = gid >> 11;
    float run = 0.f;
#pragma unroll
    for (int s = 0; s < SEG_; ++s) {
        size_t idx = ((size_t)b * SEG_ + s) * T_ + j;
        // segment rows all <= j -> contributes 0 (and may be unwritten)
        float v = (s * SEGLEN_ + SEGLEN_ - 1 <= j) ? 0.f : segsum[idx];
        segsum[idx] = run;
        run += v;
    }
}

__global__ __launch_bounds__(256) void scan_apply(
    float* __restrict__ SF, const float* __restrict__ segsum)
{
    int gid  = blockIdx.x * 256 + threadIdx.x;
    int j    = gid & (T_ - 1);
    int rest = gid >> 11;
    int seg  = rest & (SEG_ - 1);
    int b    = rest >> 4;
    if (seg * SEGLEN_ + SEGLEN_ - 1 < j) return;   // no row i>=j here; never read
    float run = segsum[((size_t)b * SEG_ + seg) * T_ + j];
    float* col = SF + (size_t)b * T_ * T_ + (size_t)(seg * SEGLEN_) * T_ + j;
#pragma unroll 4
    for (int i = 0; i < SEGLEN_; ++i) {
        float s = col[(size_t)i * T_];
        s = (seg * SEGLEN_ + i > j) ? s : 0.f;     // upper-tri SF is unwritten
        col[(size_t)i * T_] = run;                 // exclusive: FF_shifted
        run += s;
    }
}

// ---------------------------------------------------------------------------
// K5b: V -> V^T  (per (b,h): [T][64] -> [64][T]).
// ---------------------------------------------------------------------------
__global__ __launch_bounds__(256) void vt_kernel(
    const bf16_t* __restrict__ v_b, bf16_t* __restrict__ vt)
{
    __shared__ bf16_t tile[64][72];
    int t0 = blockIdx.x * 64, h = blockIdx.y, b = blockIdx.z;
    int tid = threadIdx.x;
    int r = tid >> 2, sl = tid & 3;           // r: 0..63, sl: 0..3 (16 elems each)
    const bf16_t* src = v_b + ((size_t)(b * T_ + t0 + r)) * C_ + h * HD_ + sl * 16;
    *(int4*)&tile[r][sl * 16]     = *(const int4*)src;
    *(int4*)&tile[r][sl * 16 + 8] = *(const int4*)(src + 8);
    __syncthreads();
    int hd = tid >> 2, q = tid & 3;
#pragma unroll
    for (int half = 0; half < 2; ++half) {
        int c0 = (q * 2 + half) * 8;
        union { int4 i4; bf16_t e[8]; } u;
#pragma unroll
        for (int kk = 0; kk < 8; ++kk) u.e[kk] = tile[c0 + kk][hd];
        *(int4*)(vt + ((size_t)(b * H_ + h) * HD_ + hd) * T_ + t0 + c0) = u.i4;
    }
}

// ---------------------------------------------------------------------------
// K6: double-buffered LDS flash attention (unchanged; passed round 8).
// ---------------------------------------------------------------------------
__global__ __launch_bounds__(256) void attn_kernel(
    const bf16_t* __restrict__ q_b, const bf16_t* __restrict__ k_b,
    const bf16_t* __restrict__ vt_g, const float* __restrict__ FF,
    bf16_t* __restrict__ y_b)
{
    __shared__ __align__(16) char KL[2][8192];
    __shared__ __align__(16) char VL[2][8192];
    __shared__ __align__(16) float LS[4][16][68];

    int tid = threadIdx.x, lane = tid & 63, wave = tid >> 6;
    int l15 = lane & 15, quad = lane >> 4;
    int bi = (int)gridDim.x - 1 - (int)blockIdx.x;
    int h = blockIdx.y, b = blockIdx.z;
    int i0w = bi * 64 + wave * 16;
    int jmax = bi * 64 + 63;
    const floatx4 fzero = {0.f, 0.f, 0.f, 0.f};

    const bf16_t* qrow = q_b + ((size_t)b * T_ + i0w + l15) * C_ + h * HD_;
    bf16x8 qa0 = *(const bf16x8*)(qrow + quad * 8);
    bf16x8 qa1 = *(const bf16x8*)(qrow + 32 + quad * 8);

    const bf16_t* kbase = k_b + (size_t)b * T_ * C_ + h * HD_;
    const bf16_t* vbase = vt_g + (size_t)(b * H_ + h) * HD_ * T_;
    const float*  fp    = FF + ((size_t)b * T_ + i0w + l15) * T_ + quad * 8;

    auto stage = [&](int ph, int j0) {
#pragma unroll
        for (int i = 0; i < 2; ++i) {
            int p = (wave * 2 + i) * 64 + lane;
            int r = p >> 3, sp = p & 7, s = sp ^ (r & 7);
            async_copy16(kbase + (size_t)(j0 + r) * C_ + s * 8, &KL[ph][p * 16]);
        }
#pragma unroll
        for (int i = 0; i < 2; ++i) {
            int p = (wave * 2 + i) * 64 + lane;
            int r = p >> 3, sp = p & 7, s = sp ^ (r & 7);
            async_copy16(vbase + (size_t)r * T_ + j0 + s * 8, &VL[ph][p * 16]);
        }
    };

    float m_run = -__builtin_inff(), l_run = 0.f;
    floatx4 O[4];
#pragma unroll
    for (int nt = 0; nt < 4; ++nt) O[nt] = fzero;

    stage(0, 0);
    int ph = 0;
#pragma unroll 1
    for (int j0 = 0; j0 <= jmax; j0 += 64) {
        __syncthreads();
        if (j0 + 64 <= jmax) stage(ph ^ 1, j0 + 64);

        float ffv[16];
        *(floatx4*)&ffv[0]  = *(const floatx4*)(fp);
        *(floatx4*)&ffv[4]  = *(const floatx4*)(fp + 4);
        *(floatx4*)&ffv[8]  = *(const floatx4*)(fp + 32);
        *(floatx4*)&ffv[12] = *(const floatx4*)(fp + 36);
        fp += 64;

        floatx4 pc[4];
#pragma unroll
        for (int s = 0; s < 4; ++s) {
            int r = s * 16 + l15;
            bf16x8 k0 = *(const bf16x8*)&KL[ph][r * 128 + ((quad     ^ (r & 7)) * 16)];
            bf16x8 k1 = *(const bf16x8*)&KL[ph][r * 128 + (((quad+4) ^ (r & 7)) * 16)];
            floatx4 p = mfma_bf16(qa0, k0, fzero);
            pc[s] = mfma_bf16(qa1, k1, p);
        }
#pragma unroll
        for (int s = 0; s < 4; ++s)
#pragma unroll
            for (int r = 0; r < 4; ++r)
                LS[wave][quad * 4 + r][s * 16 + l15] = pc[s][r];
        float qk[16];
        *(floatx4*)&qk[0]  = *(const floatx4*)&LS[wave][l15][quad * 8];
        *(floatx4*)&qk[4]  = *(const floatx4*)&LS[wave][l15][quad * 8 + 4];
        *(floatx4*)&qk[8]  = *(const floatx4*)&LS[wave][l15][32 + quad * 8];
        *(floatx4*)&qk[12] = *(const floatx4*)&LS[wave][l15][32 + quad * 8 + 4];

        float lg[16];
#pragma unroll
        for (int c = 0; c < 16; ++c) lg[c] = qk[c] - ffv[c];
        if (j0 + 63 > i0w) {
            int i = i0w + l15;
#pragma unroll
            for (int c = 0; c < 16; ++c) {
                int j = j0 + (c >> 3) * 32 + quad * 8 + (c & 7);
                lg[c] = (j <= i) ? lg[c] : -__builtin_inff();
            }
        }
        float rm = lg[0];
#pragma unroll
        for (int c = 1; c < 16; ++c) rm = fmaxf(rm, lg[c]);
        rm = fmaxf(rm, __shfl_xor(rm, 16));
        rm = fmaxf(rm, __shfl_xor(rm, 32));
        float mn = fmaxf(m_run, rm);
        float mnu = fmaxf(mn, -1e30f);
        float alpha = __expf(m_run - mnu);
        float p[16], ps = 0.f;
#pragma unroll
        for (int c = 0; c < 16; ++c) { p[c] = __expf(lg[c] - mnu); ps += p[c]; }
        ps += __shfl_xor(ps, 16);
        ps += __shfl_xor(ps, 32);
        l_run = l_run * alpha + ps;
        m_run = mn;
#pragma unroll
        for (int r = 0; r < 4; ++r) {
            float ar = __shfl(alpha, quad * 4 + r);
#pragma unroll
            for (int nt = 0; nt < 4; ++nt) O[nt][r] *= ar;
        }
        bf16x8 pa0, pa1;
#pragma unroll
        for (int c = 0; c < 8; ++c) { pa0[c] = (bf16_t)p[c]; pa1[c] = (bf16_t)p[8 + c]; }
#pragma unroll
        for (int nt = 0; nt < 4; ++nt) {
            int r = nt * 16 + l15;
            bf16x8 v0 = *(const bf16x8*)&VL[ph][r * 128 + ((quad     ^ (r & 7)) * 16)];
            bf16x8 v1 = *(const bf16x8*)&VL[ph][r * 128 + (((quad+4) ^ (r & 7)) * 16)];
            O[nt] = mfma_bf16(pa0, v0, O[nt]);
            O[nt] = mfma_bf16(pa1, v1, O[nt]);
        }
        ph ^= 1;
    }

#pragma unroll
    for (int r = 0; r < 4; ++r) {
        float inv = 1.f / __shfl(l_run, quad * 4 + r);
        int i = i0w + quad * 4 + r;
#pragma unroll
        for (int nt = 0; nt < 4; ++nt)
            y_b[((size_t)b * T_ + i) * C_ + h * HD_ + nt * 16 + l15] =
                (bf16_t)(O[nt][r] * inv);
    }
}

// ---------------------------------------------------------------------------
// K7: out = y @ w_proj^T + b_proj  (plain bf16, dbuf LDS — needs 32 KB!)
// ---------------------------------------------------------------------------
__global__ __launch_bounds__(256) void proj_gemm(
    const bf16_t* __restrict__ y_b, const bf16_t* __restrict__ wp_b,
    const float* __restrict__ bias, float* __restrict__ out)
{
    extern __shared__ char lds[];
    int m0 = blockIdx.x * 128, n0 = blockIdx.y * 128;
    floatx4 acc[4][4];
#pragma unroll
    for (int i = 0; i < 4; ++i)
#pragma unroll
        for (int j = 0; j < 4; ++j) acc[i][j] = (floatx4){0.f, 0.f, 0.f, 0.f};
    gemm_loop<false>((const char*)(y_b + (size_t)m0 * C_), nullptr,
                     (const char*)(wp_b + (size_t)n0 * C_), nullptr, lds, acc);

    int tid = threadIdx.x, lane = tid & 63, wave = tid >> 6;
    int l15 = lane & 15, quad = lane >> 4;
    int wr = wave >> 1, wc = wave & 1;
#pragma unroll
    for (int ni = 0; ni < 4; ++ni) {
        int col = n0 + wc * 64 + ni * 16 + l15;
        float bb = bias[col];
#pragma unroll
        for (int mi = 0; mi < 4; ++mi)
#pragma unroll
            for (int r = 0; r < 4; ++r)
                out[(size_t)(m0 + wr * 64 + mi * 16 + quad * 4 + r) * C_ + col] =
                    acc[mi][ni][r] + bb;
    }
}

// ---------------------------------------------------------------------------
extern "C" void kernel_launch(void* const* d_in, const int* in_sizes, int n_in,
                              void* d_out, int out_size, void* d_ws, size_t ws_size,
                              hipStream_t stream)
{
    const float* x      = (const float*)d_in[0];
    const float* w_attn = (const float*)d_in[1];
    const float* b_attn = (const float*)d_in[2];
    const float* w_proj = (const float*)d_in[3];
    const float* b_proj = (const float*)d_in[4];
    const float* sel_w  = (const float*)d_in[5];
    float* out = (float*)d_out;

    char* ws = (char*)d_ws;
    size_t off = 0;
    auto alloc = [&](size_t bytes) {
        void* p = ws + off;
        off += (bytes + 255) & ~(size_t)255;
        return p;
    };
    const size_t MC2 = (size_t)M_ * C_ * 2;          // 6.29 MB
    // Persistent region
    bf16_t* q_hi   = (bf16_t*)alloc(MC2);
    bf16_t* q_lo   = (bf16_t*)alloc(MC2);
    bf16_t* kw_hi  = (bf16_t*)alloc(MC2);   // dead after s_gemm -> reused as vt
    bf16_t* kw_lo  = (bf16_t*)alloc(MC2);
    bf16_t* k_b    = (bf16_t*)alloc(MC2);
    bf16_t* v_b    = (bf16_t*)alloc(MC2);
    bf16_t* y_b    = (bf16_t*)alloc(MC2);
    bf16_t* wp_b   = (bf16_t*)alloc((size_t)C_ * C_ * 2);
    float*  segsum = (float*)alloc((size_t)B_ * SEG_ * T_ * 4);
    // Aliased region: phase-1 splits and SF never live simultaneously
    char* shared_base = (char*)alloc((size_t)B_ * T_ * T_ * 4);   // 33.55 MB
    bf16_t* x_hi = (bf16_t*)shared_base;
    bf16_t* x_lo = (bf16_t*)(shared_base + MC2);
    bf16_t* w_hi = (bf16_t*)(shared_base + 2 * MC2);
    bf16_t* w_lo = (bf16_t*)(shared_base + 2 * MC2 + (size_t)N3_ * C_ * 2);
    float*  SF   = (float*)shared_base;
    bf16_t* vt   = kw_hi;   // alias: vt_kernel runs after s_gemm's last read

    int nx = M_ * C_, nw = N3_ * C_, np = C_ * C_;
    split_f32<<<dim3((nx + 255) / 256), 256, 0, stream>>>(x, x_hi, x_lo, nx);
    split_f32<<<dim3((nw + 255) / 256), 256, 0, stream>>>(w_attn, w_hi, w_lo, nw);
    conv_f32<<<dim3((np + 255) / 256), 256, 0, stream>>>(w_proj, wp_b, np);

    qkv_gemm<<<dim3(M_ / 128, N3_ / 128), 256, 65536, stream>>>(
        x_hi, x_lo, w_hi, w_lo, b_attn, sel_w,
        q_hi, q_lo, kw_hi, kw_lo, k_b, v_b);
    s_gemm<<<dim3(136, 1, B_), 256, 65536, stream>>>(
        q_hi, q_lo, kw_hi, kw_lo, SF, segsum);
    vt_kernel<<<dim3(T_ / 64, H_, B_), 256, 0, stream>>>(v_b, vt);
    scan_seg_excl<<<dim3(B_ * T_ / 256), 256, 0, stream>>>(segsum);
    scan_apply<<<dim3(B_ * SEG_ * T_ / 256), 256, 0, stream>>>(SF, segsum);
    attn_kernel<<<dim3(T_ / 64, H_, B_), 256, 0, stream>>>(q_hi, k_b, vt, SF, y_b);
    proj_gemm<<<dim3(M_ / 128, C_ / 128), 256, 32768, stream>>>(y_b, wp_b, b_proj, out);
}